// Round 1
// baseline (2557.792 us; speedup 1.0000x reference)
//
#include <hip/hip_runtime.h>
#include <hip/hip_bf16.h>

#define NR 32768      // N_ROLES
#define DIM 512
#define NE 524288     // N_EDGES
#define NL 64         // N_LLMS

// ---------------- workspace layout (bytes) ----------------
#define O_WT    ((size_t)0)                    // 512*512*4 = 1 MB   : W_gcn left-half transposed [k][j]
#define O_LLMT  ((size_t)1048576)              // 512*64*4 = 128 KB  : normalized llm, transposed [j][m]
#define O_QW    ((size_t)(1048576+131072))     // 512*8 = 4 KB       : q @ W_q^T (f64)
#define O_DEG   ((size_t)(1179648+4096))       // 32768*8            : degree sums (f64)  [zeroed]
#define O_CNT   ((size_t)(1183744+262144))     // 32768*4            : in-degree counts   [zeroed]
#define O_CUR   ((size_t)(1445888+131072))     // 32768*4            : scatter cursors    [zeroed]
#define O_LOGP  ((size_t)(1576960+131072))     // 8 (pad 256)        : logp accumulator   [zeroed]
#define O_DINV  ((size_t)(1708032+256))        // 32768*8            : 1/sqrt(deg+1) (f64)
#define O_S     ((size_t)(1708288+262144))     // 32768*8            : sum of norms per node (f64)
#define O_PTR   ((size_t)(1970432+262144))     // 32769*4 (pad)      : CSR col_ptr
#define O_EW    ((size_t)(2232576+131328))     // 524288*4           : edge weights (f32)
#define O_PERM  ((size_t)(2363904+2097152))    // 524288*4           : CSR edge permutation
#define O_A     ((size_t)(4461056+2097152))    // 32768*512*4 = 64MB : aggregated role features (f32)
#define ZERO_OFF O_DEG
#define ZERO_SZ  (O_DINV - O_DEG)              // 524544 bytes

// ---------------- threefry2x32, key = (0, 42) ----------------
__device__ __forceinline__ unsigned rotl32(unsigned x, int r) {
  return (x << r) | (x >> (32 - r));
}
__device__ __forceinline__ void tf2x32(unsigned c0, unsigned c1, unsigned& o0, unsigned& o1) {
  const unsigned k0 = 0u, k1 = 42u;
  const unsigned k2 = 0x1BD11BDAu ^ k0 ^ k1;
  unsigned x0 = c0 + k0, x1 = c1 + k1;
  x0 += x1; x1 = rotl32(x1, 13); x1 ^= x0;
  x0 += x1; x1 = rotl32(x1, 15); x1 ^= x0;
  x0 += x1; x1 = rotl32(x1, 26); x1 ^= x0;
  x0 += x1; x1 = rotl32(x1, 6);  x1 ^= x0;
  x0 += k1; x1 += k2 + 1u;
  x0 += x1; x1 = rotl32(x1, 17); x1 ^= x0;
  x0 += x1; x1 = rotl32(x1, 29); x1 ^= x0;
  x0 += x1; x1 = rotl32(x1, 16); x1 ^= x0;
  x0 += x1; x1 = rotl32(x1, 24); x1 ^= x0;
  x0 += k2; x1 += k0 + 2u;
  x0 += x1; x1 = rotl32(x1, 13); x1 ^= x0;
  x0 += x1; x1 = rotl32(x1, 15); x1 ^= x0;
  x0 += x1; x1 = rotl32(x1, 26); x1 ^= x0;
  x0 += x1; x1 = rotl32(x1, 6);  x1 ^= x0;
  x0 += k0; x1 += k1 + 3u;
  x0 += x1; x1 = rotl32(x1, 17); x1 ^= x0;
  x0 += x1; x1 = rotl32(x1, 29); x1 ^= x0;
  x0 += x1; x1 = rotl32(x1, 16); x1 ^= x0;
  x0 += x1; x1 = rotl32(x1, 24); x1 ^= x0;
  x0 += k1; x1 += k2 + 4u;
  x0 += x1; x1 = rotl32(x1, 13); x1 ^= x0;
  x0 += x1; x1 = rotl32(x1, 15); x1 ^= x0;
  x0 += x1; x1 = rotl32(x1, 26); x1 ^= x0;
  x0 += x1; x1 = rotl32(x1, 6);  x1 ^= x0;
  o0 = x0 + k2;
  o1 = x1 + k0 + 5u;
}

// ---------------- P1: llm encode + l2norm, store transposed [j][m] ----------------
__global__ void k_llm(const float* __restrict__ llm_emb, const float* __restrict__ W_llm,
                      const float* __restrict__ b_llm, float* __restrict__ llmT) {
  const int m = blockIdx.x;   // 0..63
  const int j = threadIdx.x;  // 0..511
  const float* e = llm_emb + (size_t)m * DIM;
  const float* w = W_llm + (size_t)j * DIM;
  double acc = (double)b_llm[j];
#pragma unroll 8
  for (int k = 0; k < DIM; ++k) acc += (double)e[k] * (double)w[k];
  __shared__ double red[8];
  __shared__ double nrm_s;
  double sq = acc * acc;
  sq += __shfl_down(sq, 32);
  sq += __shfl_down(sq, 16);
  sq += __shfl_down(sq, 8);
  sq += __shfl_down(sq, 4);
  sq += __shfl_down(sq, 2);
  sq += __shfl_down(sq, 1);
  const int wave = j >> 6, lane = j & 63;
  if (lane == 0) red[wave] = sq;
  __syncthreads();
  if (j == 0) {
    double s = 0.0;
    for (int w8 = 0; w8 < 8; ++w8) s += red[w8];
    nrm_s = fmax(sqrt(s), 1e-12);
  }
  __syncthreads();
  llmT[(size_t)j * NL + m] = (float)(acc / nrm_s);
}

// ---------------- P2: qW[j] = q . W_gcn[j, 512:1024] ----------------
__global__ void k_qw(const float* __restrict__ q, const float* __restrict__ W_gcn,
                     double* __restrict__ qW) {
  const int j = threadIdx.x;
  const float* w = W_gcn + (size_t)j * (2 * DIM) + DIM;
  double acc = 0.0;
#pragma unroll 8
  for (int k = 0; k < DIM; ++k) acc += (double)q[k] * (double)w[k];
  qW[j] = acc;
}

// ---------------- P3: Wt[k][j] = W_gcn[j][k] (left half) ----------------
__global__ void k_wt(const float* __restrict__ W_gcn, float* __restrict__ Wt) {
  const int t = blockIdx.x * 512 + threadIdx.x;  // 262144
  const int k = t >> 9, j = t & 511;
  Wt[(size_t)k * DIM + j] = W_gcn[(size_t)j * (2 * DIM) + k];
}

// ---------------- K1: edge weights (1 wave per edge) ----------------
__global__ void k_ew(const float* __restrict__ ee, const float* __restrict__ Wew,
                     const float* __restrict__ bew, float* __restrict__ ew,
                     float* __restrict__ outEw) {
  const int lane = threadIdx.x & 63;
  const int wv = threadIdx.x >> 6;
  const size_t e = (size_t)blockIdx.x * 4 + wv;
  const float4* row = (const float4*)(ee + e * DIM);
  const float4* w4 = (const float4*)Wew;
  float4 a0 = row[lane];
  float4 a1 = row[lane + 64];
  float4 w0 = w4[lane];
  float4 w1 = w4[lane + 64];
  double acc = (double)a0.x * (double)w0.x + (double)a0.y * (double)w0.y
             + (double)a0.z * (double)w0.z + (double)a0.w * (double)w0.w
             + (double)a1.x * (double)w1.x + (double)a1.y * (double)w1.y
             + (double)a1.z * (double)w1.z + (double)a1.w * (double)w1.w;
  acc += __shfl_xor(acc, 1);
  acc += __shfl_xor(acc, 2);
  acc += __shfl_xor(acc, 4);
  acc += __shfl_xor(acc, 8);
  acc += __shfl_xor(acc, 16);
  acc += __shfl_xor(acc, 32);
  if (lane == 0) {
    float v = (float)(acc + (double)bew[0]);
    v = fmaxf(v, 0.0f);
    ew[e] = v;
    outEw[e] = v;
  }
}

// ---------------- K2: histogram + weighted degree ----------------
__global__ void k_hist(const int* __restrict__ col, const float* __restrict__ ew,
                       unsigned* __restrict__ cnt, double* __restrict__ deg) {
  const int e = blockIdx.x * 512 + threadIdx.x;
  const int d = col[e];
  atomicAdd(&cnt[d], 1u);
  __hip_atomic_fetch_add(&deg[d], (double)ew[e], __ATOMIC_RELAXED, __HIP_MEMORY_SCOPE_AGENT);
}

// ---------------- K3: dinv = 1/sqrt(deg + 1) ----------------
__global__ void k_dinv(const double* __restrict__ deg, double* __restrict__ dinv) {
  const int i = blockIdx.x * 512 + threadIdx.x;
  dinv[i] = 1.0 / sqrt(deg[i] + 1.0);
}

// ---------------- K4: exclusive scan of counts -> col_ptr (single block) --------
__global__ void k_scan(const unsigned* __restrict__ cnt, unsigned* __restrict__ ptr) {
  __shared__ unsigned sums[1024];
  const int tid = threadIdx.x;
  const int base = tid * 32;
  unsigned loc[32];
  unsigned s = 0;
#pragma unroll
  for (int i = 0; i < 32; ++i) { loc[i] = cnt[base + i]; s += loc[i]; }
  sums[tid] = s;
  __syncthreads();
  for (int off = 1; off < 1024; off <<= 1) {
    unsigned v = 0;
    if (tid >= off) v = sums[tid - off];
    __syncthreads();
    sums[tid] += v;
    __syncthreads();
  }
  unsigned run = sums[tid] - s;  // exclusive prefix of this chunk
#pragma unroll
  for (int i = 0; i < 32; ++i) { ptr[base + i] = run; run += loc[i]; }
  if (tid == 1023) ptr[NR] = run;
}

// ---------------- K5: scatter edge ids into CSR buckets ----------------
__global__ void k_scatter(const int* __restrict__ col, const unsigned* __restrict__ ptr,
                          unsigned* __restrict__ cur, unsigned* __restrict__ perm) {
  const int e = blockIdx.x * 512 + threadIdx.x;
  const int d = col[e];
  const unsigned pos = atomicAdd(&cur[d], 1u);
  perm[ptr[d] + pos] = (unsigned)e;
}

// ---------------- K6: input-space aggregation (1 node / 128-thread block) -------
__global__ void k_agg(const float* __restrict__ role, const int* __restrict__ eiRow,
                      const float* __restrict__ ew, const double* __restrict__ dinv,
                      const unsigned* __restrict__ ptr, const unsigned* __restrict__ perm,
                      float* __restrict__ A, double* __restrict__ S) {
  const int c = blockIdx.x;
  const int t = threadIdx.x;  // dims 4t..4t+3
  const double dc = dinv[c];
  const double d2 = dc * dc;
  const float4* rc = (const float4*)(role + (size_t)c * DIM);
  float4 r = rc[t];
  double a0 = d2 * (double)r.x, a1 = d2 * (double)r.y;
  double a2 = d2 * (double)r.z, a3 = d2 * (double)r.w;
  double sn = d2;
  const unsigned beg = ptr[c], end = ptr[c + 1];
  for (unsigned k = beg; k < end; ++k) {
    const unsigned e = perm[k];
    const int rs = eiRow[e];
    const double nrm = dinv[rs] * (double)ew[e] * dc;
    const float4* rr = (const float4*)(role + (size_t)rs * DIM);
    float4 v = rr[t];
    a0 += nrm * (double)v.x; a1 += nrm * (double)v.y;
    a2 += nrm * (double)v.z; a3 += nrm * (double)v.w;
    sn += nrm;
  }
  ((float4*)(A + (size_t)c * DIM))[t] =
      make_float4((float)a0, (float)a1, (float)a2, (float)a3);
  if (t == 0) S[c] = sn;
}

// ---------------- sampling helper (one wave = one node's 64 logits) -------------
__device__ __forceinline__ void sample_one(int cg, double z, int m,
                                           float* __restrict__ outIdx,
                                           double* __restrict__ logpAcc) {
  double zmax = z;
  zmax = fmax(zmax, __shfl_xor(zmax, 1));
  zmax = fmax(zmax, __shfl_xor(zmax, 2));
  zmax = fmax(zmax, __shfl_xor(zmax, 4));
  zmax = fmax(zmax, __shfl_xor(zmax, 8));
  zmax = fmax(zmax, __shfl_xor(zmax, 16));
  zmax = fmax(zmax, __shfl_xor(zmax, 32));
  const double ex = exp(z - zmax);
  double sum = ex;
  sum += __shfl_xor(sum, 1);
  sum += __shfl_xor(sum, 2);
  sum += __shfl_xor(sum, 4);
  sum += __shfl_xor(sum, 8);
  sum += __shfl_xor(sum, 16);
  sum += __shfl_xor(sum, 32);
  const double logp = (z - zmax) - log(sum);
  // gumbel noise, jax threefry_partitionable bit layout:
  // element i -> counter (hi=0, lo=i), take first output word.
  // (fallback if output 0 mismatches: legacy split-iota layout)
  const unsigned i = (unsigned)cg * 64u + (unsigned)m;
  unsigned o0, o1;
  tf2x32(0u, i, o0, o1);
  const unsigned bits = o0;
  const float f = __uint_as_float((bits >> 9) | 0x3f800000u) - 1.0f;
  const float u = (f > 0.0f) ? f : 1.17549435e-38f;  // f32 tiny clamp, as jax uniform
  const double g = -log(-log((double)u));
  double bv = logp + g;
  int bi = m;
  // butterfly argmax with first-index tie-break (matches jnp.argmax)
#pragma unroll
  for (int s = 1; s < 64; s <<= 1) {
    const double ov = __shfl_xor(bv, s);
    const int oi = __shfl_xor(bi, s);
    if (ov > bv || (ov == bv && oi < bi)) { bv = ov; bi = oi; }
  }
  const double p = ex / sum;
  const double psel = __shfl(p, bi);
  if (m == 0) {
    outIdx[cg] = (float)bi;
    __hip_atomic_fetch_add(logpAcc, log(psel + 1e-5),
                           __ATOMIC_RELAXED, __HIP_MEMORY_SCOPE_AGENT);
  }
}

// ---------------- K7: fused GEMM (f64 acc) + l2norm + logits + sampling ---------
__launch_bounds__(512, 4)
__global__ void k_main(const float* __restrict__ A, const float* __restrict__ Wt,
                       const double* __restrict__ qW, const float* __restrict__ b_gcn,
                       const double* __restrict__ S, const float* __restrict__ llmT,
                       float* __restrict__ outIdx, double* __restrict__ logpAcc) {
  __shared__ float rqe_s[16 * DIM];   // 32 KB
  __shared__ float lc[64 * NL];       // 16 KB llm chunk
  __shared__ double red[16][9];
  __shared__ double Ss[16];
  __shared__ double rnorm[16];
  const int j = threadIdx.x;
  const int c0 = blockIdx.x << 4;
  if (j < 16) Ss[j] = S[c0 + j];
  double y[16];
#pragma unroll
  for (int c = 0; c < 16; ++c) y[c] = 0.0;
  for (int k = 0; k < DIM; k += 4) {
    const float w0 = Wt[(size_t)(k + 0) * DIM + j];
    const float w1 = Wt[(size_t)(k + 1) * DIM + j];
    const float w2 = Wt[(size_t)(k + 2) * DIM + j];
    const float w3 = Wt[(size_t)(k + 3) * DIM + j];
    const double d0 = (double)w0, d1 = (double)w1, d2 = (double)w2, d3 = (double)w3;
#pragma unroll
    for (int c = 0; c < 16; ++c) {
      // wave-uniform address -> scalar loads
      const float* Ar = A + (((size_t)(c0 + c)) << 9) + k;
      y[c] += d0 * (double)Ar[0] + d1 * (double)Ar[1]
            + d2 * (double)Ar[2] + d3 * (double)Ar[3];
    }
  }
  __syncthreads();
  {
    const double qwj = qW[j];
    const double bj = (double)b_gcn[j];
#pragma unroll
    for (int c = 0; c < 16; ++c) y[c] += Ss[c] * qwj + bj;
  }
  const int wave = j >> 6, lane = j & 63;
#pragma unroll
  for (int c = 0; c < 16; ++c) {
    double sq = y[c] * y[c];
    sq += __shfl_xor(sq, 1);
    sq += __shfl_xor(sq, 2);
    sq += __shfl_xor(sq, 4);
    sq += __shfl_xor(sq, 8);
    sq += __shfl_xor(sq, 16);
    sq += __shfl_xor(sq, 32);
    if (lane == 0) red[c][wave] = sq;
  }
  __syncthreads();
  if (j < 16) {
    double s = 0.0;
#pragma unroll
    for (int w = 0; w < 8; ++w) s += red[j][w];
    rnorm[j] = 1.0 / fmax(sqrt(s), 1e-12);
  }
  __syncthreads();
#pragma unroll
  for (int c = 0; c < 16; ++c) rqe_s[c * DIM + j] = (float)(y[c] * rnorm[c]);

  // logits: wave w handles nodes (w, w+8); lane = llm index m
  const int m = lane;
  const int cA = wave, cB = wave + 8;
  double accA = 0.0, accB = 0.0;
  for (int j0 = 0; j0 < DIM; j0 += 64) {
    __syncthreads();  // also covers rqe_s readiness on first pass
#pragma unroll
    for (int ii = 0; ii < 8; ++ii) {
      const int idx = ii * 512 + j;  // = row*64 + m'
      lc[idx] = llmT[(size_t)(j0 + (idx >> 6)) * NL + (idx & 63)];
    }
    __syncthreads();
#pragma unroll
    for (int jj = 0; jj < 64; jj += 4) {
      const float4 rA = *(const float4*)&rqe_s[cA * DIM + j0 + jj];
      const float4 rB = *(const float4*)&rqe_s[cB * DIM + j0 + jj];
      const float l0 = lc[(jj + 0) * 64 + m];
      const float l1 = lc[(jj + 1) * 64 + m];
      const float l2 = lc[(jj + 2) * 64 + m];
      const float l3 = lc[(jj + 3) * 64 + m];
      accA += (double)rA.x * (double)l0 + (double)rA.y * (double)l1
            + (double)rA.z * (double)l2 + (double)rA.w * (double)l3;
      accB += (double)rB.x * (double)l0 + (double)rB.y * (double)l1
            + (double)rB.z * (double)l2 + (double)rB.w * (double)l3;
    }
  }
  sample_one(c0 + cA, accA, m, outIdx, logpAcc);
  sample_one(c0 + cB, accB, m, outIdx, logpAcc);
}

// ---------------- K8: edge index copy-out + logp write ----------------
__global__ void k_copy(const int* __restrict__ ei, const double* __restrict__ logpAcc,
                       float* __restrict__ out) {
  const int t = blockIdx.x * 512 + threadIdx.x;  // 0 .. 2*NE-1
  out[NR + 1 + t] = (float)ei[t];
  if (t == 0) out[NR] = (float)(*logpAcc);
}

extern "C" void kernel_launch(void* const* d_in, const int* in_sizes, int n_in,
                              void* d_out, int out_size, void* d_ws, size_t ws_size,
                              hipStream_t stream) {
  const float* q     = (const float*)d_in[0];
  const float* role  = (const float*)d_in[1];
  const int*   ei    = (const int*)d_in[2];   // [2][NE], int32 (jax x64 off)
  const float* ee    = (const float*)d_in[3];
  const float* llm_e = (const float*)d_in[4];
  const float* W_llm = (const float*)d_in[5];
  const float* b_llm = (const float*)d_in[6];
  const float* W_ew  = (const float*)d_in[7];
  const float* b_ew  = (const float*)d_in[8];
  const float* W_gcn = (const float*)d_in[9];
  const float* b_gcn = (const float*)d_in[10];
  float* out = (float*)d_out;
  char* ws = (char*)d_ws;

  float*    Wt    = (float*)(ws + O_WT);
  float*    llmT  = (float*)(ws + O_LLMT);
  double*   qW    = (double*)(ws + O_QW);
  double*   deg   = (double*)(ws + O_DEG);
  unsigned* cnt   = (unsigned*)(ws + O_CNT);
  unsigned* cur   = (unsigned*)(ws + O_CUR);
  double*   logp  = (double*)(ws + O_LOGP);
  double*   dinv  = (double*)(ws + O_DINV);
  double*   S     = (double*)(ws + O_S);
  unsigned* ptr   = (unsigned*)(ws + O_PTR);
  float*    ew    = (float*)(ws + O_EW);
  unsigned* perm  = (unsigned*)(ws + O_PERM);
  float*    A     = (float*)(ws + O_A);

  float* outIdx  = out;             // [NR]
  float* outEdge = out + NR + 1;    // [2*NE]
  float* outEw   = out + NR + 1 + 2 * NE;  // [NE]

  const int* eiRow = ei;
  const int* eiCol = ei + NE;

  hipMemsetAsync(ws + ZERO_OFF, 0, ZERO_SZ, stream);

  k_llm<<<64, 512, 0, stream>>>(llm_e, W_llm, b_llm, llmT);
  k_qw<<<1, 512, 0, stream>>>(q, W_gcn, qW);
  k_wt<<<512, 512, 0, stream>>>(W_gcn, Wt);
  k_ew<<<NE / 4, 256, 0, stream>>>(ee, W_ew, b_ew, ew, outEw);
  k_hist<<<NE / 512, 512, 0, stream>>>(eiCol, ew, cnt, deg);
  k_dinv<<<NR / 512, 512, 0, stream>>>(deg, dinv);
  k_scan<<<1, 1024, 0, stream>>>(cnt, ptr);
  k_scatter<<<NE / 512, 512, 0, stream>>>(eiCol, ptr, cur, perm);
  k_agg<<<NR, 128, 0, stream>>>(role, eiRow, ew, dinv, ptr, perm, A, S);
  k_main<<<NR / 16, 512, 0, stream>>>(A, Wt, qW, b_gcn, S, llmT, outIdx, logp);
  k_copy<<<(2 * NE) / 512, 512, 0, stream>>>(ei, logp, out);
}

// Round 2
// 1995.530 us; speedup vs baseline: 1.2818x; 1.2818x over previous
//
#include <hip/hip_runtime.h>

#define NR 32768      // N_ROLES
#define DIM 512
#define NE 524288     // N_EDGES
#define NL 64         // N_LLMS

typedef __attribute__((ext_vector_type(8))) short short8;
typedef __attribute__((ext_vector_type(4))) float f32x4;

// ---------------- workspace layout (bytes) ----------------
#define O_WTH   ((size_t)0)          // 524288  : W_gcn left half, bf16 [j][k]
#define O_LLMT  ((size_t)524288)     // 131072  : normalized llm f32, [j][m]
#define O_QW    ((size_t)655360)     // 4096    : q @ W_q^T (f32) [512]
#define O_DEG   ((size_t)659456)     // 131072  : weighted degree f32     [zero]
#define O_CNT   ((size_t)790528)     // 131072  : in-degree counts        [zero]
#define O_CUR   ((size_t)921600)     // 131072  : scatter cursors         [zero]
#define O_LOGP  ((size_t)1052672)    // 256     : logp accumulator f64    [zero]
#define O_DINV  ((size_t)1052928)    // 131072  : 1/sqrt(deg+1) f32
#define O_S     ((size_t)1184000)    // 131072  : per-node norm sum f32
#define O_PTR   ((size_t)1315072)    // 131328  : CSR col_ptr [NR+1]
#define O_ROWP  ((size_t)1446400)    // 2097152 : CSR source-row ids (tmpL overlays)
#define O_WN    ((size_t)3543552)    // 2097152 : CSR folded edge norms f32
#define O_A     ((size_t)5640704)    // 33554432: aggregated features bf16 [NR][512]
#define O_ROLEH ((size_t)39195136)   // 33554432: role bf16; Y bf16 overlays after k_agg
// END = 72749568 bytes (69.4 MiB) < 73667072 proven available in round 1
#define O_TMPL  O_ROWP               // llm raw dots f32 [64][512] (dead before k_scatter)
#define ZERO_OFF O_DEG
#define ZERO_SZ  ((size_t)(1052928 - 659456))   // deg+cnt+cur+logp

// ---------------- bf16 helpers (RNE) ----------------
__device__ __forceinline__ unsigned short f2bf(float f) {
  unsigned u = __float_as_uint(f);
  u += 0x7fffu + ((u >> 16) & 1u);
  return (unsigned short)(u >> 16);
}
__device__ __forceinline__ float bf2f(unsigned short h) {
  return __uint_as_float(((unsigned)h) << 16);
}

// ---------------- threefry2x32, key = (0, 42) ----------------
__device__ __forceinline__ unsigned rotl32(unsigned x, int r) {
  return (x << r) | (x >> (32 - r));
}
__device__ __forceinline__ void tf2x32(unsigned c0, unsigned c1, unsigned& o0, unsigned& o1) {
  const unsigned k0 = 0u, k1 = 42u;
  const unsigned k2 = 0x1BD11BDAu ^ k0 ^ k1;
  unsigned x0 = c0 + k0, x1 = c1 + k1;
  x0 += x1; x1 = rotl32(x1, 13); x1 ^= x0;
  x0 += x1; x1 = rotl32(x1, 15); x1 ^= x0;
  x0 += x1; x1 = rotl32(x1, 26); x1 ^= x0;
  x0 += x1; x1 = rotl32(x1, 6);  x1 ^= x0;
  x0 += k1; x1 += k2 + 1u;
  x0 += x1; x1 = rotl32(x1, 17); x1 ^= x0;
  x0 += x1; x1 = rotl32(x1, 29); x1 ^= x0;
  x0 += x1; x1 = rotl32(x1, 16); x1 ^= x0;
  x0 += x1; x1 = rotl32(x1, 24); x1 ^= x0;
  x0 += k2; x1 += k0 + 2u;
  x0 += x1; x1 = rotl32(x1, 13); x1 ^= x0;
  x0 += x1; x1 = rotl32(x1, 15); x1 ^= x0;
  x0 += x1; x1 = rotl32(x1, 26); x1 ^= x0;
  x0 += x1; x1 = rotl32(x1, 6);  x1 ^= x0;
  x0 += k0; x1 += k1 + 3u;
  x0 += x1; x1 = rotl32(x1, 17); x1 ^= x0;
  x0 += x1; x1 = rotl32(x1, 29); x1 ^= x0;
  x0 += x1; x1 = rotl32(x1, 16); x1 ^= x0;
  x0 += x1; x1 = rotl32(x1, 24); x1 ^= x0;
  x0 += k1; x1 += k2 + 4u;
  x0 += x1; x1 = rotl32(x1, 13); x1 ^= x0;
  x0 += x1; x1 = rotl32(x1, 15); x1 ^= x0;
  x0 += x1; x1 = rotl32(x1, 26); x1 ^= x0;
  x0 += x1; x1 = rotl32(x1, 6);  x1 ^= x0;
  o0 = x0 + k2;
  o1 = x1 + k0 + 5u;
}

// ---------------- casts ----------------
__global__ void k_cast_w(const float* __restrict__ W_gcn, unsigned short* __restrict__ WtH) {
  const int t = blockIdx.x * 512 + threadIdx.x;    // 65536
  const int j = t >> 7, kq = (t & 127) * 4;
  float4 v = *(const float4*)&W_gcn[(size_t)j * 1024 + kq];
  ushort4 o;
  o.x = f2bf(v.x); o.y = f2bf(v.y); o.z = f2bf(v.z); o.w = f2bf(v.w);
  *(ushort4*)&WtH[(size_t)j * 512 + kq] = o;
}

__global__ void k_castrole(const float* __restrict__ role, unsigned short* __restrict__ roleH) {
  const size_t t = ((size_t)blockIdx.x * 512 + threadIdx.x) * 8;  // 16.7M elems
  float4 a = *(const float4*)&role[t];
  float4 b = *(const float4*)&role[t + 4];
  ushort4 o0, o1;
  o0.x = f2bf(a.x); o0.y = f2bf(a.y); o0.z = f2bf(a.z); o0.w = f2bf(a.w);
  o1.x = f2bf(b.x); o1.y = f2bf(b.y); o1.z = f2bf(b.z); o1.w = f2bf(b.w);
  *(ushort4*)&roleH[t] = o0;
  *(ushort4*)&roleH[t + 4] = o1;
}

// ---------------- llm encoder ----------------
__global__ void k_llm_dot(const float* __restrict__ llm_emb, const float* __restrict__ W_llm,
                          const float* __restrict__ b_llm, float* __restrict__ tmpL) {
  const int wv = blockIdx.x * 8 + (threadIdx.x >> 6);  // 32768 waves
  const int lane = threadIdx.x & 63;
  const int m = wv >> 9, j = wv & 511;
  const float4* e4 = (const float4*)&llm_emb[(size_t)m * DIM];
  const float4* w4 = (const float4*)&W_llm[(size_t)j * DIM];
  float4 a0 = e4[lane * 2], a1 = e4[lane * 2 + 1];
  float4 b0 = w4[lane * 2], b1 = w4[lane * 2 + 1];
  float acc = a0.x * b0.x + a0.y * b0.y + a0.z * b0.z + a0.w * b0.w
            + a1.x * b1.x + a1.y * b1.y + a1.z * b1.z + a1.w * b1.w;
  acc += __shfl_xor(acc, 1);
  acc += __shfl_xor(acc, 2);
  acc += __shfl_xor(acc, 4);
  acc += __shfl_xor(acc, 8);
  acc += __shfl_xor(acc, 16);
  acc += __shfl_xor(acc, 32);
  if (lane == 0) tmpL[(size_t)m * DIM + j] = acc + b_llm[j];
}

__global__ void k_llm_norm(const float* __restrict__ tmpL, float* __restrict__ llmT) {
  const int m = blockIdx.x, j = threadIdx.x;
  const float v = tmpL[(size_t)m * DIM + j];
  float sq = v * v;
  sq += __shfl_xor(sq, 1);
  sq += __shfl_xor(sq, 2);
  sq += __shfl_xor(sq, 4);
  sq += __shfl_xor(sq, 8);
  sq += __shfl_xor(sq, 16);
  sq += __shfl_xor(sq, 32);
  __shared__ float red[8];
  __shared__ float nrm_s;
  const int wave = j >> 6, lane = j & 63;
  if (lane == 0) red[wave] = sq;
  __syncthreads();
  if (j == 0) {
    float s = 0.f;
    for (int w = 0; w < 8; ++w) s += red[w];
    nrm_s = fmaxf(sqrtf(s), 1e-12f);
  }
  __syncthreads();
  llmT[(size_t)j * NL + m] = v / nrm_s;
}

// ---------------- qW[j] = q . W_gcn[j, 512:1024] ----------------
__global__ void k_qw(const float* __restrict__ q, const float* __restrict__ W_gcn,
                     float* __restrict__ qW) {
  const int j = blockIdx.x * 8 + (threadIdx.x >> 6);  // 512 waves
  const int lane = threadIdx.x & 63;
  const float4* q4 = (const float4*)q;
  const float4* w4 = (const float4*)&W_gcn[(size_t)j * 1024 + 512];
  float4 a0 = q4[lane * 2], a1 = q4[lane * 2 + 1];
  float4 b0 = w4[lane * 2], b1 = w4[lane * 2 + 1];
  float acc = a0.x * b0.x + a0.y * b0.y + a0.z * b0.z + a0.w * b0.w
            + a1.x * b1.x + a1.y * b1.y + a1.z * b1.z + a1.w * b1.w;
  acc += __shfl_xor(acc, 1);
  acc += __shfl_xor(acc, 2);
  acc += __shfl_xor(acc, 4);
  acc += __shfl_xor(acc, 8);
  acc += __shfl_xor(acc, 16);
  acc += __shfl_xor(acc, 32);
  if (lane == 0) qW[j] = acc;
}

// ---------------- edge weights + degree (fused) ----------------
__global__ void k_ew(const float* __restrict__ ee, const float* __restrict__ Wew,
                     const float* __restrict__ bew, const int* __restrict__ eiCol,
                     float* __restrict__ outEw, unsigned* __restrict__ cnt,
                     float* __restrict__ deg) {
  const int lane = threadIdx.x & 63;
  const int wv = threadIdx.x >> 6;
  const size_t e = (size_t)blockIdx.x * 4 + wv;
  const float4* row = (const float4*)(ee + e * DIM);
  const float4* w4 = (const float4*)Wew;
  float4 a0 = row[lane], a1 = row[lane + 64];
  float4 w0 = w4[lane], w1 = w4[lane + 64];
  float acc = a0.x * w0.x + a0.y * w0.y + a0.z * w0.z + a0.w * w0.w
            + a1.x * w1.x + a1.y * w1.y + a1.z * w1.z + a1.w * w1.w;
  acc += __shfl_xor(acc, 1);
  acc += __shfl_xor(acc, 2);
  acc += __shfl_xor(acc, 4);
  acc += __shfl_xor(acc, 8);
  acc += __shfl_xor(acc, 16);
  acc += __shfl_xor(acc, 32);
  if (lane == 0) {
    float v = fmaxf(acc + bew[0], 0.0f);
    outEw[e] = v;
    const int d = eiCol[e];
    atomicAdd(&cnt[d], 1u);
    atomicAdd(&deg[d], v);
  }
}

// ---------------- dinv ----------------
__global__ void k_dinv(const float* __restrict__ deg, float* __restrict__ dinv) {
  const int i = blockIdx.x * 512 + threadIdx.x;
  dinv[i] = 1.0f / sqrtf(deg[i] + 1.0f);
}

// ---------------- exclusive scan of counts -> col_ptr ----------------
__global__ void k_scan(const unsigned* __restrict__ cnt, unsigned* __restrict__ ptr) {
  __shared__ unsigned sums[1024];
  const int tid = threadIdx.x;
  const int base = tid * 32;
  unsigned loc[32];
  unsigned s = 0;
#pragma unroll
  for (int i = 0; i < 32; ++i) { loc[i] = cnt[base + i]; s += loc[i]; }
  sums[tid] = s;
  __syncthreads();
  for (int off = 1; off < 1024; off <<= 1) {
    unsigned v = 0;
    if (tid >= off) v = sums[tid - off];
    __syncthreads();
    sums[tid] += v;
    __syncthreads();
  }
  unsigned run = sums[tid] - s;
#pragma unroll
  for (int i = 0; i < 32; ++i) { ptr[base + i] = run; run += loc[i]; }
  if (tid == 1023) ptr[NR] = run;
}

// ---------------- scatter: fold norms, CSR-order ----------------
__global__ void k_scatter(const int* __restrict__ eiRow, const int* __restrict__ eiCol,
                          const float* __restrict__ ew, const float* __restrict__ dinv,
                          const unsigned* __restrict__ ptr, unsigned* __restrict__ cur,
                          int* __restrict__ rowP, float* __restrict__ wn) {
  const int e = blockIdx.x * 512 + threadIdx.x;
  const int d = eiCol[e];
  const int r = eiRow[e];
  const unsigned pos = atomicAdd(&cur[d], 1u);
  const unsigned slot = ptr[d] + pos;
  rowP[slot] = r;
  wn[slot] = dinv[r] * ew[e] * dinv[d];
}

// ---------------- aggregation (input space, bf16 gathers) ----------------
__global__ void k_agg(const unsigned short* __restrict__ roleH, const int* __restrict__ rowP,
                      const float* __restrict__ wn, const float* __restrict__ dinv,
                      const unsigned* __restrict__ ptr, unsigned short* __restrict__ A,
                      float* __restrict__ S) {
  const int c = blockIdx.x;
  const int t = threadIdx.x;  // dims 4t..4t+3
  const float dc = dinv[c];
  const float d2 = dc * dc;
  ushort4 r = *(const ushort4*)&roleH[(size_t)c * DIM + 4 * t];
  float a0 = d2 * bf2f(r.x), a1 = d2 * bf2f(r.y);
  float a2 = d2 * bf2f(r.z), a3 = d2 * bf2f(r.w);
  float sn = d2;
  const unsigned beg = ptr[c], end = ptr[c + 1];
  for (unsigned k = beg; k < end; ++k) {
    const int rs = rowP[k];
    const float w = wn[k];
    ushort4 v = *(const ushort4*)&roleH[(size_t)rs * DIM + 4 * t];
    a0 += w * bf2f(v.x); a1 += w * bf2f(v.y);
    a2 += w * bf2f(v.z); a3 += w * bf2f(v.w);
    sn += w;
  }
  ushort4 o;
  o.x = f2bf(a0); o.y = f2bf(a1); o.z = f2bf(a2); o.w = f2bf(a3);
  *(ushort4*)&A[(size_t)c * DIM + 4 * t] = o;
  if (t == 0) S[c] = sn;
}

// ---------------- MFMA GEMM: Y = A @ WtH^T (bf16 in, bf16 out) ----------------
// 128x128 tile, BK=64, 256 threads (2x2 waves of 64x64), 16x16x32 bf16 MFMA.
__launch_bounds__(256, 2)
__global__ void k_gemm(const unsigned short* __restrict__ A, const unsigned short* __restrict__ B,
                       unsigned short* __restrict__ Y) {
  __shared__ short sA[128 * 64];
  __shared__ short sB[128 * 64];
  const int tid = threadIdx.x;
  const int lane = tid & 63, wv = tid >> 6;
  const int wm = wv & 1, wn = wv >> 1;
  const int r0 = (blockIdx.x >> 2) * 128;
  const int c0 = (blockIdx.x & 3) * 128;

  f32x4 acc[4][4];
#pragma unroll
  for (int i = 0; i < 4; ++i)
#pragma unroll
    for (int j = 0; j < 4; ++j) acc[i][j] = (f32x4)(0.0f);

  const int fr = lane & 15, fq = lane >> 4;  // fragment row, quad
  for (int k0 = 0; k0 < DIM; k0 += 64) {
    __syncthreads();
#pragma unroll
    for (int r = 0; r < 4; ++r) {
      const int eo = r * 2048 + tid * 8;
      const int row = eo >> 6, col = eo & 63;
      *(short8*)&sA[eo] = *(const short8*)&A[(size_t)(r0 + row) * DIM + k0 + col];
      *(short8*)&sB[eo] = *(const short8*)&B[(size_t)(c0 + row) * DIM + k0 + col];
    }
    __syncthreads();
#pragma unroll
    for (int s = 0; s < 2; ++s) {
      short8 af[4], bf[4];
#pragma unroll
      for (int tm = 0; tm < 4; ++tm)
        af[tm] = *(const short8*)&sA[(wm * 64 + tm * 16 + fr) * 64 + s * 32 + fq * 8];
#pragma unroll
      for (int tn = 0; tn < 4; ++tn)
        bf[tn] = *(const short8*)&sB[(wn * 64 + tn * 16 + fr) * 64 + s * 32 + fq * 8];
#pragma unroll
      for (int tm = 0; tm < 4; ++tm)
#pragma unroll
        for (int tn = 0; tn < 4; ++tn)
          acc[tm][tn] = __builtin_amdgcn_mfma_f32_16x16x32_bf16(af[tm], bf[tn], acc[tm][tn], 0, 0, 0);
    }
  }
  // epilogue: C/D layout col=lane&15, row=(lane>>4)*4+reg
#pragma unroll
  for (int tm = 0; tm < 4; ++tm) {
#pragma unroll
    for (int tn = 0; tn < 4; ++tn) {
      const int col = c0 + wn * 64 + tn * 16 + fr;
      const int rowb = r0 + wm * 64 + tm * 16 + fq * 4;
#pragma unroll
      for (int r = 0; r < 4; ++r)
        Y[(size_t)(rowb + r) * DIM + col] = f2bf(acc[tm][tn][r]);
    }
  }
}

// ---------------- sampling helper (one wave = one node's 64 logits) -------------
__device__ __forceinline__ void sample_one(int cg, double z, int m,
                                           float* __restrict__ outIdx,
                                           double* __restrict__ logpAcc) {
  double zmax = z;
  zmax = fmax(zmax, __shfl_xor(zmax, 1));
  zmax = fmax(zmax, __shfl_xor(zmax, 2));
  zmax = fmax(zmax, __shfl_xor(zmax, 4));
  zmax = fmax(zmax, __shfl_xor(zmax, 8));
  zmax = fmax(zmax, __shfl_xor(zmax, 16));
  zmax = fmax(zmax, __shfl_xor(zmax, 32));
  const double ex = exp(z - zmax);
  double sum = ex;
  sum += __shfl_xor(sum, 1);
  sum += __shfl_xor(sum, 2);
  sum += __shfl_xor(sum, 4);
  sum += __shfl_xor(sum, 8);
  sum += __shfl_xor(sum, 16);
  sum += __shfl_xor(sum, 32);
  const unsigned i = (unsigned)cg * 64u + (unsigned)m;
  unsigned o0, o1;
  tf2x32(0u, i, o0, o1);
  const float f = __uint_as_float((o0 >> 9) | 0x3f800000u) - 1.0f;
  const float u = (f > 0.0f) ? f : 1.17549435e-38f;
  const double g = -log(-log((double)u));
  const double logp = (z - zmax) - log(sum);
  double bv = logp + g;
  int bi = m;
#pragma unroll
  for (int s = 1; s < 64; s <<= 1) {
    const double ov = __shfl_xor(bv, s);
    const int oi = __shfl_xor(bi, s);
    if (ov > bv || (ov == bv && oi < bi)) { bv = ov; bi = oi; }
  }
  const double p = ex / sum;
  const double psel = __shfl(p, bi);
  if (m == 0) {
    outIdx[cg] = (float)bi;
    __hip_atomic_fetch_add(logpAcc, log(psel + 1e-5),
                           __ATOMIC_RELAXED, __HIP_MEMORY_SCOPE_AGENT);
  }
}

// ---------------- epilogue: +bias, l2norm, logits, sample ----------------
__launch_bounds__(512)
__global__ void k_post(const unsigned short* __restrict__ Y, const float* __restrict__ S,
                       const float* __restrict__ qW, const float* __restrict__ b_gcn,
                       const float* __restrict__ llmT, float* __restrict__ outIdx,
                       double* __restrict__ logpAcc) {
  __shared__ float rqe_s[16 * DIM];   // 32 KB
  __shared__ float lc[64 * NL];       // 16 KB
  __shared__ float red[16][9];
  __shared__ float Ss[16];
  __shared__ float rn[16];
  const int j = threadIdx.x;
  const int c0 = blockIdx.x << 4;
  if (j < 16) Ss[j] = S[c0 + j];
  float y[16];
#pragma unroll
  for (int c = 0; c < 16; ++c) y[c] = bf2f(Y[(size_t)(c0 + c) * DIM + j]);
  __syncthreads();
  {
    const float qwj = qW[j];
    const float bj = b_gcn[j];
#pragma unroll
    for (int c = 0; c < 16; ++c) y[c] += Ss[c] * qwj + bj;
  }
  const int wave = j >> 6, lane = j & 63;
#pragma unroll
  for (int c = 0; c < 16; ++c) {
    float sq = y[c] * y[c];
    sq += __shfl_xor(sq, 1);
    sq += __shfl_xor(sq, 2);
    sq += __shfl_xor(sq, 4);
    sq += __shfl_xor(sq, 8);
    sq += __shfl_xor(sq, 16);
    sq += __shfl_xor(sq, 32);
    if (lane == 0) red[c][wave] = sq;
  }
  __syncthreads();
  if (j < 16) {
    float s = 0.f;
#pragma unroll
    for (int w = 0; w < 8; ++w) s += red[j][w];
    rn[j] = 1.0f / fmaxf(sqrtf(s), 1e-12f);
  }
  __syncthreads();
#pragma unroll
  for (int c = 0; c < 16; ++c) rqe_s[c * DIM + j] = y[c] * rn[c];

  // logits: wave w handles nodes (w, w+8); lane = llm index m
  const int m = lane;
  const int cA = wave, cB = wave + 8;
  float accA = 0.f, accB = 0.f;
  for (int j0 = 0; j0 < DIM; j0 += 64) {
    __syncthreads();  // also covers rqe_s readiness on first pass
#pragma unroll
    for (int ii = 0; ii < 8; ++ii) {
      const int idx = ii * 512 + j;
      lc[idx] = llmT[(size_t)(j0 + (idx >> 6)) * NL + (idx & 63)];
    }
    __syncthreads();
#pragma unroll
    for (int jj = 0; jj < 64; jj += 4) {
      const float4 rA = *(const float4*)&rqe_s[cA * DIM + j0 + jj];
      const float4 rB = *(const float4*)&rqe_s[cB * DIM + j0 + jj];
      const float l0 = lc[(jj + 0) * 64 + m];
      const float l1 = lc[(jj + 1) * 64 + m];
      const float l2 = lc[(jj + 2) * 64 + m];
      const float l3 = lc[(jj + 3) * 64 + m];
      accA += rA.x * l0 + rA.y * l1 + rA.z * l2 + rA.w * l3;
      accB += rB.x * l0 + rB.y * l1 + rB.z * l2 + rB.w * l3;
    }
  }
  sample_one(c0 + cA, (double)accA, m, outIdx, logpAcc);
  sample_one(c0 + cB, (double)accB, m, outIdx, logpAcc);
}

// ---------------- edge index copy-out + logp write ----------------
__global__ void k_copy(const int* __restrict__ ei, const double* __restrict__ logpAcc,
                       float* __restrict__ out) {
  const int t = blockIdx.x * 512 + threadIdx.x;  // 0 .. 2*NE-1
  out[NR + 1 + t] = (float)ei[t];
  if (t == 0) out[NR] = (float)(*logpAcc);
}

extern "C" void kernel_launch(void* const* d_in, const int* in_sizes, int n_in,
                              void* d_out, int out_size, void* d_ws, size_t ws_size,
                              hipStream_t stream) {
  const float* q     = (const float*)d_in[0];
  const float* role  = (const float*)d_in[1];
  const int*   ei    = (const int*)d_in[2];
  const float* ee    = (const float*)d_in[3];
  const float* llm_e = (const float*)d_in[4];
  const float* W_llm = (const float*)d_in[5];
  const float* b_llm = (const float*)d_in[6];
  const float* W_ew  = (const float*)d_in[7];
  const float* b_ew  = (const float*)d_in[8];
  const float* W_gcn = (const float*)d_in[9];
  const float* b_gcn = (const float*)d_in[10];
  float* out = (float*)d_out;
  char* ws = (char*)d_ws;

  unsigned short* WtH   = (unsigned short*)(ws + O_WTH);
  float*          llmT  = (float*)(ws + O_LLMT);
  float*          tmpL  = (float*)(ws + O_TMPL);
  float*          qW    = (float*)(ws + O_QW);
  float*          deg   = (float*)(ws + O_DEG);
  unsigned*       cnt   = (unsigned*)(ws + O_CNT);
  unsigned*       cur   = (unsigned*)(ws + O_CUR);
  double*         logp  = (double*)(ws + O_LOGP);
  float*          dinv  = (float*)(ws + O_DINV);
  float*          S     = (float*)(ws + O_S);
  unsigned*       ptr   = (unsigned*)(ws + O_PTR);
  int*            rowP  = (int*)(ws + O_ROWP);
  float*          wn    = (float*)(ws + O_WN);
  unsigned short* A     = (unsigned short*)(ws + O_A);
  unsigned short* roleH = (unsigned short*)(ws + O_ROLEH);
  unsigned short* Y     = (unsigned short*)(ws + O_ROLEH);  // overlays roleH after k_agg

  float* outIdx = out;                     // [NR]
  float* outEw  = out + NR + 1 + 2 * NE;   // [NE]

  const int* eiRow = ei;
  const int* eiCol = ei + NE;

  hipMemsetAsync(ws + ZERO_OFF, 0, ZERO_SZ, stream);

  k_cast_w<<<128, 512, 0, stream>>>(W_gcn, WtH);
  k_castrole<<<4096, 512, 0, stream>>>(role, roleH);
  k_llm_dot<<<4096, 512, 0, stream>>>(llm_e, W_llm, b_llm, tmpL);
  k_llm_norm<<<64, 512, 0, stream>>>(tmpL, llmT);
  k_qw<<<64, 512, 0, stream>>>(q, W_gcn, qW);
  k_ew<<<NE / 4, 256, 0, stream>>>(ee, W_ew, b_ew, eiCol, outEw, cnt, deg);
  k_dinv<<<NR / 512, 512, 0, stream>>>(deg, dinv);
  k_scan<<<1, 1024, 0, stream>>>(cnt, ptr);
  k_scatter<<<NE / 512, 512, 0, stream>>>(eiRow, eiCol, outEw, dinv, ptr, cur, rowP, wn);
  k_agg<<<NR, 128, 0, stream>>>(roleH, rowP, wn, dinv, ptr, A, S);
  k_gemm<<<1024, 256, 0, stream>>>(A, WtH, Y);
  k_post<<<NR / 16, 512, 0, stream>>>(Y, S, qW, b_gcn, llmT, outIdx, logp);
  k_copy<<<(2 * NE) / 512, 512, 0, stream>>>(ei, logp, out);
}